// Round 2
// baseline (825.499 us; speedup 1.0000x reference)
//
#include <hip/hip_runtime.h>
#include <hip/hip_bf16.h>
#include <math.h>

// Problem constants (AttentionPool): B=8, N=4096, C=1536, H=24, hd=64, R=8
#define Bb 8
#define Nn 4096
#define Cc 1536
#define Hh 24
#define HD 64
#define RR 8
#define MKV (Bb * Nn)        // 32768 rows for K/V GEMM
#define NKV (2 * Cc)         // 3072 cols (K and V fused)
#define NCHUNK 16            // key chunks for split attention
#define CK 256               // keys per chunk

typedef unsigned short u16;
typedef unsigned int u32;
typedef __attribute__((ext_vector_type(2))) u32 u32x2;

typedef __attribute__((ext_vector_type(8))) short bf16x8;
typedef __attribute__((ext_vector_type(4))) float f32x4;

__device__ __forceinline__ u16 f32_to_bf16(float f) {
    union { float f; u32 u; } v; v.f = f;
    u32 r = v.u + 0x7fffu + ((v.u >> 16) & 1u);  // RNE
    return (u16)(r >> 16);
}
__device__ __forceinline__ float bflo(u32 p) {
    union { u32 u; float f; } v; v.u = p << 16; return v.f;
}
__device__ __forceinline__ float bfhi(u32 p) {
    union { u32 u; float f; } v; v.u = p & 0xffff0000u; return v.f;
}
__device__ __forceinline__ ushort4 cvt4(float4 v, float s) {
    ushort4 o;
    o.x = f32_to_bf16(v.x * s); o.y = f32_to_bf16(v.y * s);
    o.z = f32_to_bf16(v.z * s); o.w = f32_to_bf16(v.w * s);
    return o;
}

// ---------------- fused prep: casts + q gather + zero fills, one dispatch ----------------
__global__ __launch_bounds__(256)
void prep_kernel(const float* __restrict__ x,
                 const float* __restrict__ Wk, const float* __restrict__ Wv,
                 const float* __restrict__ Wq, const float* __restrict__ Wp,
                 u16* __restrict__ xb, u16* __restrict__ wkvb,
                 u16* __restrict__ wqb, u16* __restrict__ wpb,
                 u16* __restrict__ xqp, u16* __restrict__ aob,
                 float* __restrict__ dout)
{
    const int blk = blockIdx.x, tid = threadIdx.x;
    if (blk < 49152) {
        int i = blk * 256 + tid;                 // quad index < 12582912
        float4 v = ((const float4*)x)[i];
        ((ushort4*)xb)[i] = cvt4(v, 1.0f);
        int row = i / 384;                       // 384 quads per 1536-row
        int n = row & (Nn - 1);
        if (n < RR) {                            // q gather, SCALE=0.125 folded (exact)
            int b = row >> 12;
            int cq = i - row * 384;
            ((ushort4*)xqp)[(size_t)(b * RR + n) * 384 + cq] = cvt4(v, 0.125f);
        }
    } else if (blk < 58368) {
        int t = blk - 49152;
        int w = t / 2304;
        int i = (t - w * 2304) * 256 + tid;      // < 589824 quads
        const float4* src = (w == 0) ? (const float4*)Wk : (w == 1) ? (const float4*)Wv
                          : (w == 2) ? (const float4*)Wq : (const float4*)Wp;
        u16* dst = (w == 0) ? wkvb : (w == 1) ? wkvb + 2359296 : (w == 2) ? wqb : wpb;
        ((ushort4*)dst)[i] = cvt4(src[i], 1.0f);
    } else if (blk < 58464) {                    // zero xqp rows 64..127
        int i = (blk - 58368) * 256 + tid;
        ushort4 z = {0, 0, 0, 0};
        ((ushort4*)(xqp + 64 * Cc))[i] = z;
    } else if (blk < 58656) {                    // zero aob (all 128 rows)
        int i = (blk - 58464) * 256 + tid;
        ushort4 z = {0, 0, 0, 0};
        ((ushort4*)aob)[i] = z;
    } else {                                     // zero d_out (for split-K atomics)
        int i = (blk - 58656) * 256 + tid;
        float4 z = {0.f, 0.f, 0.f, 0.f};
        ((float4*)dout)[i] = z;
    }
}

// ---------------- OLD 128x128 GEMM body (kept for tiny output projection) ----------------
template <int OUT>
__device__ __forceinline__ void gemm_body64(
    const u16* __restrict__ A, const u16* __restrict__ B, void* __restrict__ Cv,
    const float* __restrict__ bias, int M_valid, int N, int K,
    int m0, int n0, int kbeg, int kend, u16* As, u16* Bs)
{
    const int tid = threadIdx.x;
    const int wave = tid >> 6, lane = tid & 63;
    const int wm = (wave & 1) * 64, wn = (wave >> 1) * 64;
    const int fm = lane & 15;
    const int kq = lane >> 4;            // 0..3

    f32x4 acc[4][4] = {};

    const u16* aptr[4]; const u16* bptr[4]; int ldsoff[4];
    #pragma unroll
    for (int off = 0; off < 4; ++off) {
        int e = tid * 8 + off * 2048;
        int r = e >> 6, cp = (e >> 3) & 7;
        int csrc = cp ^ (r & 7);
        aptr[off] = A + (size_t)(m0 + r) * K + csrc * 8;
        bptr[off] = B + (size_t)(n0 + r) * K + csrc * 8;
        ldsoff[off] = e;
    }

    for (int k0 = kbeg; k0 < kend; k0 += 64) {
        #pragma unroll
        for (int off = 0; off < 4; ++off)
            __builtin_amdgcn_global_load_lds(
                (const __attribute__((address_space(1))) void*)(aptr[off] + k0),
                (__attribute__((address_space(3))) void*)(As + ldsoff[off]), 16, 0, 0);
        #pragma unroll
        for (int off = 0; off < 4; ++off)
            __builtin_amdgcn_global_load_lds(
                (const __attribute__((address_space(1))) void*)(bptr[off] + k0),
                (__attribute__((address_space(3))) void*)(Bs + ldsoff[off]), 16, 0, 0);
        __syncthreads();

        #pragma unroll
        for (int ks = 0; ks < 2; ++ks) {
            bf16x8 af[4], bfr[4];
            #pragma unroll
            for (int i = 0; i < 4; ++i) {
                int r = wm + i * 16 + fm;
                int c = ks * 4 + kq;
                af[i] = *(const bf16x8*)&As[r * 64 + ((c ^ (r & 7)) << 3)];
            }
            #pragma unroll
            for (int j = 0; j < 4; ++j) {
                int r = wn + j * 16 + fm;
                int c = ks * 4 + kq;
                bfr[j] = *(const bf16x8*)&Bs[r * 64 + ((c ^ (r & 7)) << 3)];
            }
            #pragma unroll
            for (int i = 0; i < 4; ++i)
                #pragma unroll
                for (int j = 0; j < 4; ++j)
                    acc[i][j] = __builtin_amdgcn_mfma_f32_16x16x32_bf16(af[i], bfr[j], acc[i][j], 0, 0, 0);
        }
        __syncthreads();
    }

    const int col = lane & 15, rb = (lane >> 4) * 4;
    #pragma unroll
    for (int i = 0; i < 4; ++i)
        #pragma unroll
        for (int j = 0; j < 4; ++j)
            #pragma unroll
            for (int rg = 0; rg < 4; ++rg) {
                int m = m0 + wm + i * 16 + rb + rg;
                if (m < M_valid) {
                    int n = n0 + wn + j * 16 + col;
                    float v = acc[i][j][rg];
                    if (bias) v += bias[n];
                    size_t idx = (size_t)m * N + n;
                    if (OUT == 0)       ((float*)Cv)[idx] = v;
                    else if (OUT == 1)  ((u16*)Cv)[idx] = f32_to_bf16(v);
                    else                atomicAdd((float*)Cv + idx, v);
                }
            }
}

// ---------------- 256x256 8-phase GEMM body (T1+T2+T3/T4+T5 stack) ----------------
// C[M,N] = A[M,K]*B[N,K]^T. 512 threads = 8 waves (2M x 4N), per-wave 128x64 out.
// LDS: 2 bufs x {A,B} x {Khalf0,Khalf1}, each region [256 rows][32 elems] (64 B rows).
// Chunk swizzle within region row: 16B chunk c stored at c ^ ((row>>1)&3); applied via
// pre-swizzled GLOBAL source + swizzled ds_read addr (LDS dest linear, rule 21).
//
// Stage units (1 unit = 1 STG = 2 global_load_lds = 4 vmcnt slots), one per phase:
//   p1: A buf1 ks1 (T+1 K1)    p2: B buf1 ks1
//   p3: A buf0 ks0 (T+2 K0)    p4: B buf0 ks0
//   p5: A buf0 ks1 (T+2 K1)    p6: B buf0 ks1
//   p7: A buf1 ks0 (T+3 K0)    p8: B buf1 ks0
// Reads: p1/2 <- buf0ks0, p3/4 <- buf0ks1, p5/6 <- buf1ks0, p7/8 <- buf1ks1.
// Wait discipline (round-2 fix: drain late, drain little):
//   steady state: vmcnt(8) at p2/p4/p6/p8 — outstanding is always 12 loads there;
//   draining to 8 retires exactly the unit-pair read one phase later, issued 4-5
//   phases earlier (~6000 cy >> HBM latency -> near-free wait).
//   last iteration (no p3..p8 stages): p2 vmcnt(8) [12 out], p4 vmcnt(4) [8 out],
//   p6 vmcnt(0) [4 out, drains p1/p2's T+1-K1 before p7 reads it], p8 none.
// vmcnt placed after MFMA, before the phase's 2nd barrier, so all waves have
// drained before any wave's next-phase ds_reads (vmcnt is per-wave).
#define VM8 asm volatile("s_waitcnt vmcnt(8)" ::: "memory")
#define VM4 asm volatile("s_waitcnt vmcnt(4)" ::: "memory")
#define VM0 asm volatile("s_waitcnt vmcnt(0)" ::: "memory")

#define STG(MAT, BUF, KS, KOFF) do {                                                   \
    const u16* _s0 = ((MAT) == 0 ? sA0 : sB0) + (KOFF);                                \
    const u16* _s1 = ((MAT) == 0 ? sA1 : sB1) + (KOFF);                                \
    u16* _d = lds + (BUF) * 32768 + (MAT) * 16384 + (KS) * 8192;                       \
    __builtin_amdgcn_global_load_lds(                                                  \
        (const __attribute__((address_space(1))) void*)_s0,                            \
        (__attribute__((address_space(3))) void*)(_d + dst0), 16, 0, 0);               \
    __builtin_amdgcn_global_load_lds(                                                  \
        (const __attribute__((address_space(1))) void*)_s1,                            \
        (__attribute__((address_space(3))) void*)(_d + dst1), 16, 0, 0);               \
} while (0)

// Phase: stage first (loads enter the pipe early), then ds_read frags, barrier,
// lgkmcnt(0)+sched fence, prio-boosted MFMA cluster, counted vmcnt, barrier.
#define PH(BUF, KS, MH, DOB, STG_STMT, VW) do {                                        \
    STG_STMT;                                                                          \
    if (DOB) {                                                                         \
        _Pragma("unroll")                                                              \
        for (int j = 0; j < 4; ++j)                                                    \
            bfr[j] = *(const bf16x8*)(lds + (BUF) * 32768 + 16384 + (KS) * 8192        \
                                          + bRd + j * 512);                            \
    }                                                                                  \
    _Pragma("unroll")                                                                  \
    for (int ii = 0; ii < 4; ++ii)                                                     \
        af[ii] = *(const bf16x8*)(lds + (BUF) * 32768 + (KS) * 8192                    \
                                      + aRd + ((MH) + ii) * 512);                      \
    __builtin_amdgcn_s_barrier();                                                      \
    asm volatile("s_waitcnt lgkmcnt(0)" ::: "memory");                                 \
    __builtin_amdgcn_sched_barrier(0);                                                 \
    __builtin_amdgcn_s_setprio(1);                                                     \
    _Pragma("unroll")                                                                  \
    for (int ii = 0; ii < 4; ++ii)                                                     \
        _Pragma("unroll")                                                              \
        for (int j = 0; j < 4; ++j)                                                    \
            acc[(MH) + ii][j] = __builtin_amdgcn_mfma_f32_16x16x32_bf16(               \
                af[ii], bfr[j], acc[(MH) + ii][j], 0, 0, 0);                            \
    __builtin_amdgcn_s_setprio(0);                                                     \
    VW;                                                                                \
    __builtin_amdgcn_s_barrier();                                                      \
} while (0)

template <int OUT>
__device__ __forceinline__ void gemm256_body(
    const u16* __restrict__ A, const u16* __restrict__ B, void* __restrict__ Cv,
    int M_valid, int N, int K, int m0, int n0, u16* lds)
{
    const int tid = threadIdx.x;
    const int lane = tid & 63;
    const int w = tid >> 6;
    const int wr = w >> 2, wc = w & 3;           // wave grid 2M x 4N
    const int fm = lane & 15, kq = lane >> 4;

    // staging: thread t covers region row (t>>2) [+128 for inst1], chunk t&3.
    const int ra = tid >> 2;
    const int csrc = (tid & 3) ^ ((tid >> 3) & 3);
    const u16* sA0 = A + (size_t)(m0 + ra) * K + csrc * 8;
    const u16* sA1 = A + (size_t)(m0 + 128 + ra) * K + csrc * 8;
    const u16* sB0 = B + (size_t)(n0 + ra) * K + csrc * 8;
    const u16* sB1 = B + (size_t)(n0 + 128 + ra) * K + csrc * 8;
    const int dst0 = tid * 8, dst1 = 4096 + tid * 8;   // elems (16 B / thread)

    // ds_read bases (elems). Row R = wbase + frag*16 + fm; (R>>1)&3 == (fm>>1)&3.
    const int swz = (fm >> 1) & 3;
    const int aRd = (wr * 128 + fm) * 32 + ((kq ^ swz) << 3);
    const int bRd = (wc * 64 + fm) * 32 + ((kq ^ swz) << 3);

    f32x4 acc[8][4] = {};
    bf16x8 af[4], bfr[4];

    // prologue: stage T0 {A-K0,B-K0,A-K1,B-K1} + T1 {A-K0,B-K0};
    // drain only T0-K0 (needed at p1): vmcnt(8) leaves 4 units in flight.
    STG(0, 0, 0, 0);
    STG(1, 0, 0, 0);
    STG(0, 0, 1, 32);
    STG(1, 0, 1, 32);
    STG(0, 1, 0, 64);
    STG(1, 1, 0, 64);
    VM8;
    __builtin_amdgcn_s_barrier();

    const int NITER = K >> 7;                    // 2 K-tiles (BK=64) per iteration
    #pragma unroll 1
    for (int it = 0; it < NITER; ++it) {
        const int kT1 = (it * 2 + 1) * 64;
        const int kT2 = kT1 + 64, kT3 = kT1 + 128;
        const bool ok = (it < NITER - 1);
        PH(0, 0, 0, true,  STG(0, 1, 1, kT1 + 32), );
        PH(0, 0, 4, false, STG(1, 1, 1, kT1 + 32), VM8);
        PH(0, 1, 0, true,  if (ok) STG(0, 0, 0, kT2), );
        PH(0, 1, 4, false, if (ok) STG(1, 0, 0, kT2),
           if (ok) { VM8; } else { VM4; });
        PH(1, 0, 0, true,  if (ok) STG(0, 0, 1, kT2 + 32), );
        PH(1, 0, 4, false, if (ok) STG(1, 0, 1, kT2 + 32),
           if (ok) { VM8; } else { VM0; });
        PH(1, 1, 0, true,  if (ok) STG(0, 1, 0, kT3), );
        PH(1, 1, 4, false, if (ok) STG(1, 1, 0, kT3),
           if (ok) { VM8; });
    }

    // C/D layout: col = lane&15, row = (lane>>4)*4 + reg  [m89, verified]
    const int col = lane & 15, rb2 = (lane >> 4) * 4;
    #pragma unroll
    for (int ii = 0; ii < 8; ++ii)
        #pragma unroll
        for (int j = 0; j < 4; ++j)
            #pragma unroll
            for (int rg = 0; rg < 4; ++rg) {
                int m = m0 + wr * 128 + ii * 16 + rb2 + rg;
                if (m < M_valid) {
                    int n = n0 + wc * 64 + j * 16 + col;
                    float v = acc[ii][j][rg];
                    size_t idx = (size_t)m * N + n;
                    if (OUT == 0) ((float*)Cv)[idx] = v;
                    else          ((u16*)Cv)[idx] = f32_to_bf16(v);
                }
            }
}

// blocks 0..1535: KV proj, XCD-swizzled (1536 % 8 == 0, bijective), n fastest per XCD.
// blocks 1536..1541: q proj (M padded; rows 128..255 read adjacent ws garbage, unstored).
__global__ __launch_bounds__(512, 2)
void gemm_main(const u16* __restrict__ xqp, const u16* __restrict__ wqb,
               float* __restrict__ qout,
               const u16* __restrict__ xb, const u16* __restrict__ wkvb,
               u16* __restrict__ kvb)
{
    __shared__ u16 lds[65536];                   // 128 KiB
    const int blk = blockIdx.x;
    if (blk < 1536) {
        int g = blk & 7, s = blk >> 3;           // 192 blocks per XCD class
        int mb = g * 16 + s / 12, nb = s % 12;
        gemm256_body<1>(xb, wkvb, kvb, MKV, NKV, Cc, mb * 256, nb * 256, lds);
    } else {
        int nb = blk - 1536;
        gemm256_body<0>(xqp, wqb, qout, 64, Cc, Cc, 0, nb * 256, lds);
    }
}

// ---------------- output projection, split-K x4 with f32 atomics (old 128^2 body) -------
__global__ __launch_bounds__(256, 3)
void gemm_out(const u16* __restrict__ aob, const u16* __restrict__ wpb,
              float* __restrict__ out, const float* __restrict__ bp)
{
    __shared__ u16 As[128 * 64];
    __shared__ u16 Bs[128 * 64];
    const int nb = blockIdx.x;                   // 0..11
    const int z = blockIdx.y;                    // 0..3
    gemm_body64<2>(aob, wpb, out, (z == 0) ? bp : nullptr,
                   64, Cc, Cc, 0, nb * 128, z * 384, (z + 1) * 384, As, Bs);
}

// ---------------- split attention: grid (NCHUNK, B*H), 256 keys per block ----------------
__global__ __launch_bounds__(256)
void attn_part_kernel(const float* __restrict__ qout, const u16* __restrict__ kv,
                      const int* __restrict__ mask,
                      float* __restrict__ opart, float* __restrict__ mstat,
                      float* __restrict__ lstat)
{
    const int chunk = blockIdx.x;       // 0..15
    const int bh = blockIdx.y;          // 0..191
    const int b = bh / Hh, h = bh - b * Hh;
    const int tid = threadIdx.x;

    __shared__ u16  Vs[CK * HD];        // 32 KB
    __shared__ float Ps[RR][CK];        // 8 KB
    __shared__ float qs[RR * HD];       // 2 KB

    for (int i = tid; i < RR * HD; i += 256)
        qs[i] = qout[(size_t)(b * RR + (i >> 6)) * Cc + h * HD + (i & 63)];
    __syncthreads();

    // V-chunk DMA (overlaps QK^T; drained by the next barrier)
    {
        const u16* vsrc = kv + (size_t)(b * Nn + chunk * CK) * NKV + Cc + h * HD;
        const int vr = tid >> 3, vc = (tid & 7) * 8;
        #pragma unroll
        for (int i = 0; i < 8; ++i) {
            __builtin_amdgcn_global_load_lds(
                (const __attribute__((address_space(1))) void*)(vsrc + (size_t)(i * 32 + vr) * NKV + vc),
                (__attribute__((address_space(3))) void*)(Vs + i * 2048 + tid * 8), 16, 0, 0);
        }
    }

    // phase A: thread = key; masked scores
    {
        const int j = chunk * CK + tid;
        float s[RR] = {0, 0, 0, 0, 0, 0, 0, 0};
        const u16* krow = kv + (size_t)(b * Nn + j) * NKV + h * HD;
        #pragma unroll
        for (int c = 0; c < 8; ++c) {
            uint4 kvec = *(const uint4*)(krow + c * 8);
            float kf0 = bflo(kvec.x), kf1 = bfhi(kvec.x);
            float kf2 = bflo(kvec.y), kf3 = bfhi(kvec.y);
            float kf4 = bflo(kvec.z), kf5 = bfhi(kvec.z);
            float kf6 = bflo(kvec.w), kf7 = bfhi(kvec.w);
            #pragma unroll
            for (int r = 0; r < RR; ++r) {
                const float4 qa = *(const float4*)&qs[r * HD + c * 8];
                const float4 qb = *(const float4*)&qs[r * HD + c * 8 + 4];
                s[r] += qa.x * kf0 + qa.y * kf1 + qa.z * kf2 + qa.w * kf3
                      + qb.x * kf4 + qb.y * kf5 + qb.z * kf6 + qb.w * kf7;
            }
        }
        #pragma unroll
        for (int r = 0; r < RR; ++r) {
            bool keep = (j < RR) ? (j == r)
                                 : (mask[(size_t)(b * RR + r) * (Nn - RR) + (j - RR)] != 0);
            Ps[r][tid] = keep ? s[r] : -INFINITY;
        }
    }
    __syncthreads();

    // phase A2: per-row chunk max & exp-sum
    {
        const int r = tid >> 5, g = tid & 31;
        float vals[CK / 32];
        float mx = -INFINITY;
        #pragma unroll
        for (int i = 0; i < CK / 32; ++i) {
            vals[i] = Ps[r][g + 32 * i];
            mx = fmaxf(mx, vals[i]);
        }
        #pragma unroll
        for (int m = 16; m >= 1; m >>= 1) mx = fmaxf(mx, __shfl_xor(mx, m));
        const float mfin = fmaxf(mx, -1e30f);
        float sum = 0.f;
        #pragma unroll
        for (int i = 0; i < CK / 32; ++i) {
            float e = __expf(vals[i] - mfin);
            Ps[r][g + 32 * i] = e;
            sum += e;
        }
        #pragma unroll
        for (int m = 16; m >= 1; m >>= 1) sum += __shfl_xor(sum, m);
        if (g == 0) {
            size_t si = ((size_t)bh * NCHUNK + chunk) * RR + r;
            mstat[si] = mx;
            lstat[si] = sum;
        }
    }
    __syncthreads();

    // phase B: o[r,d] = sum_k P[r,k] * V[k,d]
    {
        const int r  = tid >> 5;
        const int g  = tid & 31;
        const int kh = g >> 4;
        const int d4 = (g & 15) * 4;
        float a0 = 0.f, a1 = 0.f, a2 = 0.f, a3 = 0.f;
        const float* pr = &Ps[r][kh * 128];
        const u16* vb = Vs + kh * 128 * HD + d4;
        #pragma unroll 2
        for (int k4 = 0; k4 < 32; ++k4) {
            f32x4 pv = *(const f32x4*)(pr + k4 * 4);
            #pragma unroll
            for (int t = 0; t < 4; ++t) {
                float p = pv[t];
                u32x2 vv = *(const u32x2*)(vb + (k4 * 4 + t) * HD);
                a0 += p * bflo(vv.x); a1 += p * bfhi(vv.x);
                a2 += p * bflo(vv.y); a3 += p * bfhi(vv.y);
            }
        }
        a0 += __shfl_xor(a0, 16); a1 += __shfl_xor(a1, 16);
        a2 += __shfl_xor(a2, 16); a3 += __shfl_xor(a3, 16);
        if (kh == 0) {
            size_t po = ((size_t)bh * NCHUNK + chunk) * (RR * HD) + r * HD + d4;
            float4 o = {a0, a1, a2, a3};
            *(float4*)(opart + po) = o;
        }
    }
}

// ---------------- combine partials -> bf16 attention output ----------------
__global__ __launch_bounds__(256)
void attn_combine_kernel(const float* __restrict__ opart, const float* __restrict__ mstat,
                         const float* __restrict__ lstat, u16* __restrict__ aob)
{
    int idx = blockIdx.x * 256 + threadIdx.x;   // < 64*1536
    int row = idx / Cc, col = idx - row * Cc;
    int b = row >> 3, r = row & 7;
    int h = col >> 6, d = col & 63;
    int bh = b * Hh + h;
    float M = -INFINITY;
    #pragma unroll
    for (int c = 0; c < NCHUNK; ++c)
        M = fmaxf(M, mstat[((size_t)bh * NCHUNK + c) * RR + r]);
    float L = 0.f, O = 0.f;
    #pragma unroll
    for (int c = 0; c < NCHUNK; ++c) {
        size_t si = ((size_t)bh * NCHUNK + c) * RR + r;
        float w = __expf(mstat[si] - M);
        L += w * lstat[si];
        O += w * opart[((size_t)bh * NCHUNK + c) * (RR * HD) + r * HD + d];
    }
    aob[(size_t)row * Cc + col] = f32_to_bf16(O / L);
}

// ---------------- launch ----------------
extern "C" void kernel_launch(void* const* d_in, const int* in_sizes, int n_in,
                              void* d_out, int out_size, void* d_ws, size_t ws_size,
                              hipStream_t stream)
{
    const float* x    = (const float*)d_in[0];
    const int*   mask = (const int*)d_in[1];
    const float* Wq   = (const float*)d_in[2];
    const float* Wk   = (const float*)d_in[3];
    const float* Wv   = (const float*)d_in[4];
    const float* Wp   = (const float*)d_in[5];
    const float* bp   = (const float*)d_in[6];

    char* ws = (char*)d_ws;
    u16*   xb     = (u16*)(ws);                       // 100,663,296  x bf16 [32768,1536]
    u16*   wkvb   = (u16*)(ws + 100663296);           //   9,437,184  [Wk;Wv] bf16 [3072,1536]
    u16*   wqb    = (u16*)(ws + 110100480);           //   4,718,592  Wq bf16
    u16*   wpb    = (u16*)(ws + 114819072);           //   4,718,592  Wp bf16
    u16*   kvb    = (u16*)(ws + 119537664);           // 201,326,592  kv bf16 [32768,3072]
    u16*   xqp    = (u16*)(ws + 320864256);           //     393,216  q input padded [128,1536]
    float* qout   = (float*)(ws + 321257472);         //     786,432  q proj f32 [128,1536]
    u16*   aob    = (u16*)(ws + 322043904);           //     393,216  attn out padded [128,1536]
    // partials alias xb (dead after KV GEMM)
    float* opart  = (float*)(ws);                     // 6,291,456 B
    float* mstat  = (float*)(ws + 6291456);           // 98,304 B
    float* lstat  = (float*)(ws + 6389760);           // 98,304 B

    // 1: all casts + q gather + zero fills
    prep_kernel<<<58752, 256, 0, stream>>>(x, Wk, Wv, Wq, Wp, xb, wkvb, wqb, wpb,
                                           xqp, aob, (float*)d_out);
    // 2: fused K/V proj (256^2 8-phase, blocks 0..1535) + q proj (blocks 1536..1541)
    gemm_main<<<1542, 512, 0, stream>>>(xqp, wqb, qout, xb, wkvb, kvb);
    // 3: split attention
    attn_part_kernel<<<dim3(NCHUNK, Bb * Hh), 256, 0, stream>>>(qout, kvb, mask,
                                                                opart, mstat, lstat);
    // 4: combine
    attn_combine_kernel<<<384, 256, 0, stream>>>(opart, mstat, lstat, aob);
    // 5: output projection, split-K atomics (d_out zeroed by prep)
    gemm_out<<<dim3(12, 4), 256, 0, stream>>>(aob, wpb, (float*)d_out, bp);
}

// Round 3
// 601.176 us; speedup vs baseline: 1.3731x; 1.3731x over previous
//
#include <hip/hip_runtime.h>
#include <hip/hip_bf16.h>
#include <math.h>

// Problem constants (AttentionPool): B=8, N=4096, C=1536, H=24, hd=64, R=8
#define Bb 8
#define Nn 4096
#define Cc 1536
#define Hh 24
#define HD 64
#define RR 8
#define MKV (Bb * Nn)        // 32768 rows for V GEMM
#define ACH 32               // key chunks for split attention
#define CKK 128              // keys per chunk

typedef unsigned short u16;
typedef unsigned int u32;
typedef __attribute__((ext_vector_type(2))) u32 u32x2;

typedef __attribute__((ext_vector_type(8))) short bf16x8;
typedef __attribute__((ext_vector_type(4))) float f32x4;

__device__ __forceinline__ u16 f32_to_bf16(float f) {
    union { float f; u32 u; } v; v.f = f;
    u32 r = v.u + 0x7fffu + ((v.u >> 16) & 1u);  // RNE
    return (u16)(r >> 16);
}
__device__ __forceinline__ float bflo(u32 p) {
    union { u32 u; float f; } v; v.u = p << 16; return v.f;
}
__device__ __forceinline__ float bfhi(u32 p) {
    union { u32 u; float f; } v; v.u = p & 0xffff0000u; return v.f;
}
__device__ __forceinline__ ushort4 cvt4(float4 v, float s) {
    ushort4 o;
    o.x = f32_to_bf16(v.x * s); o.y = f32_to_bf16(v.y * s);
    o.z = f32_to_bf16(v.z * s); o.w = f32_to_bf16(v.w * s);
    return o;
}

// ---------------- fused prep: casts + q gather + zero fills, one dispatch ----------------
__global__ __launch_bounds__(256)
void prep_kernel(const float* __restrict__ x,
                 const float* __restrict__ Wk, const float* __restrict__ Wv,
                 const float* __restrict__ Wq, const float* __restrict__ Wp,
                 u16* __restrict__ xb, u16* __restrict__ wkvb,
                 u16* __restrict__ wqb, u16* __restrict__ wpb,
                 u16* __restrict__ xqp, u16* __restrict__ aob,
                 float* __restrict__ dout)
{
    const int blk = blockIdx.x, tid = threadIdx.x;
    if (blk < 49152) {
        int i = blk * 256 + tid;                 // quad index < 12582912
        float4 v = ((const float4*)x)[i];
        ((ushort4*)xb)[i] = cvt4(v, 1.0f);
        int row = i / 384;                       // 384 quads per 1536-row
        int n = row & (Nn - 1);
        if (n < RR) {                            // q gather, SCALE=0.125 folded (exact)
            int b = row >> 12;
            int cq = i - row * 384;
            ((ushort4*)xqp)[(size_t)(b * RR + n) * 384 + cq] = cvt4(v, 0.125f);
        }
    } else if (blk < 58368) {
        int t = blk - 49152;
        int w = t / 2304;
        int i = (t - w * 2304) * 256 + tid;      // < 589824 quads
        const float4* src = (w == 0) ? (const float4*)Wk : (w == 1) ? (const float4*)Wv
                          : (w == 2) ? (const float4*)Wq : (const float4*)Wp;
        u16* dst = (w == 0) ? wkvb : (w == 1) ? wkvb + 2359296 : (w == 2) ? wqb : wpb;
        ((ushort4*)dst)[i] = cvt4(src[i], 1.0f);
    } else if (blk < 58464) {                    // zero xqp rows 64..127
        int i = (blk - 58368) * 256 + tid;
        ushort4 z = {0, 0, 0, 0};
        ((ushort4*)(xqp + 64 * Cc))[i] = z;
    } else if (blk < 58656) {                    // zero aob (all 128 rows)
        int i = (blk - 58464) * 256 + tid;
        ushort4 z = {0, 0, 0, 0};
        ((ushort4*)aob)[i] = z;
    } else {                                     // zero d_out (for split-K atomics)
        int i = (blk - 58656) * 256 + tid;
        float4 z = {0.f, 0.f, 0.f, 0.f};
        ((float4*)dout)[i] = z;
    }
}

// ---------------- 128x128 GEMM body (kept for tiny output projection) ----------------
template <int OUT>
__device__ __forceinline__ void gemm_body64(
    const u16* __restrict__ A, const u16* __restrict__ B, void* __restrict__ Cv,
    const float* __restrict__ bias, int M_valid, int N, int K,
    int m0, int n0, int kbeg, int kend, u16* As, u16* Bs)
{
    const int tid = threadIdx.x;
    const int wave = tid >> 6, lane = tid & 63;
    const int wm = (wave & 1) * 64, wn = (wave >> 1) * 64;
    const int fm = lane & 15;
    const int kq = lane >> 4;            // 0..3

    f32x4 acc[4][4] = {};

    const u16* aptr[4]; const u16* bptr[4]; int ldsoff[4];
    #pragma unroll
    for (int off = 0; off < 4; ++off) {
        int e = tid * 8 + off * 2048;
        int r = e >> 6, cp = (e >> 3) & 7;
        int csrc = cp ^ (r & 7);
        aptr[off] = A + (size_t)(m0 + r) * K + csrc * 8;
        bptr[off] = B + (size_t)(n0 + r) * K + csrc * 8;
        ldsoff[off] = e;
    }

    for (int k0 = kbeg; k0 < kend; k0 += 64) {
        #pragma unroll
        for (int off = 0; off < 4; ++off)
            __builtin_amdgcn_global_load_lds(
                (const __attribute__((address_space(1))) void*)(aptr[off] + k0),
                (__attribute__((address_space(3))) void*)(As + ldsoff[off]), 16, 0, 0);
        #pragma unroll
        for (int off = 0; off < 4; ++off)
            __builtin_amdgcn_global_load_lds(
                (const __attribute__((address_space(1))) void*)(bptr[off] + k0),
                (__attribute__((address_space(3))) void*)(Bs + ldsoff[off]), 16, 0, 0);
        __syncthreads();

        #pragma unroll
        for (int ks = 0; ks < 2; ++ks) {
            bf16x8 af[4], bfr[4];
            #pragma unroll
            for (int i = 0; i < 4; ++i) {
                int r = wm + i * 16 + fm;
                int c = ks * 4 + kq;
                af[i] = *(const bf16x8*)&As[r * 64 + ((c ^ (r & 7)) << 3)];
            }
            #pragma unroll
            for (int j = 0; j < 4; ++j) {
                int r = wn + j * 16 + fm;
                int c = ks * 4 + kq;
                bfr[j] = *(const bf16x8*)&Bs[r * 64 + ((c ^ (r & 7)) << 3)];
            }
            #pragma unroll
            for (int i = 0; i < 4; ++i)
                #pragma unroll
                for (int j = 0; j < 4; ++j)
                    acc[i][j] = __builtin_amdgcn_mfma_f32_16x16x32_bf16(af[i], bfr[j], acc[i][j], 0, 0, 0);
        }
        __syncthreads();
    }

    const int col = lane & 15, rb = (lane >> 4) * 4;
    #pragma unroll
    for (int i = 0; i < 4; ++i)
        #pragma unroll
        for (int j = 0; j < 4; ++j)
            #pragma unroll
            for (int rg = 0; rg < 4; ++rg) {
                int m = m0 + wm + i * 16 + rb + rg;
                if (m < M_valid) {
                    int n = n0 + wn + j * 16 + col;
                    float v = acc[i][j][rg];
                    if (bias) v += bias[n];
                    size_t idx = (size_t)m * N + n;
                    if (OUT == 0)       ((float*)Cv)[idx] = v;
                    else if (OUT == 1)  ((u16*)Cv)[idx] = f32_to_bf16(v);
                    else                atomicAdd((float*)Cv + idx, v);
                }
            }
}

// ---------------- 256x256 8-phase GEMM body (unchanged from round 2) ----------------
#define VM8 asm volatile("s_waitcnt vmcnt(8)" ::: "memory")
#define VM4 asm volatile("s_waitcnt vmcnt(4)" ::: "memory")
#define VM0 asm volatile("s_waitcnt vmcnt(0)" ::: "memory")

#define STG(MAT, BUF, KS, KOFF) do {                                                   \
    const u16* _s0 = ((MAT) == 0 ? sA0 : sB0) + (KOFF);                                \
    const u16* _s1 = ((MAT) == 0 ? sA1 : sB1) + (KOFF);                                \
    u16* _d = lds + (BUF) * 32768 + (MAT) * 16384 + (KS) * 8192;                       \
    __builtin_amdgcn_global_load_lds(                                                  \
        (const __attribute__((address_space(1))) void*)_s0,                            \
        (__attribute__((address_space(3))) void*)(_d + dst0), 16, 0, 0);               \
    __builtin_amdgcn_global_load_lds(                                                  \
        (const __attribute__((address_space(1))) void*)_s1,                            \
        (__attribute__((address_space(3))) void*)(_d + dst1), 16, 0, 0);               \
} while (0)

#define PH(BUF, KS, MH, DOB, STG_STMT, VW) do {                                        \
    STG_STMT;                                                                          \
    if (DOB) {                                                                         \
        _Pragma("unroll")                                                              \
        for (int j = 0; j < 4; ++j)                                                    \
            bfr[j] = *(const bf16x8*)(lds + (BUF) * 32768 + 16384 + (KS) * 8192        \
                                          + bRd + j * 512);                            \
    }                                                                                  \
    _Pragma("unroll")                                                                  \
    for (int ii = 0; ii < 4; ++ii)                                                     \
        af[ii] = *(const bf16x8*)(lds + (BUF) * 32768 + (KS) * 8192                    \
                                      + aRd + ((MH) + ii) * 512);                      \
    __builtin_amdgcn_s_barrier();                                                      \
    asm volatile("s_waitcnt lgkmcnt(0)" ::: "memory");                                 \
    __builtin_amdgcn_sched_barrier(0);                                                 \
    __builtin_amdgcn_s_setprio(1);                                                     \
    _Pragma("unroll")                                                                  \
    for (int ii = 0; ii < 4; ++ii)                                                     \
        _Pragma("unroll")                                                              \
        for (int j = 0; j < 4; ++j)                                                    \
            acc[(MH) + ii][j] = __builtin_amdgcn_mfma_f32_16x16x32_bf16(               \
                af[ii], bfr[j], acc[(MH) + ii][j], 0, 0, 0);                            \
    __builtin_amdgcn_s_setprio(0);                                                     \
    VW;                                                                                \
    __builtin_amdgcn_s_barrier();                                                      \
} while (0)

template <int OUT>
__device__ __forceinline__ void gemm256_body(
    const u16* __restrict__ A, const u16* __restrict__ B, void* __restrict__ Cv,
    int M_valid, int N, int K, int m0, int n0, u16* lds)
{
    const int tid = threadIdx.x;
    const int lane = tid & 63;
    const int w = tid >> 6;
    const int wr = w >> 2, wc = w & 3;           // wave grid 2M x 4N
    const int fm = lane & 15, kq = lane >> 4;

    const int ra = tid >> 2;
    const int csrc = (tid & 3) ^ ((tid >> 3) & 3);
    const u16* sA0 = A + (size_t)(m0 + ra) * K + csrc * 8;
    const u16* sA1 = A + (size_t)(m0 + 128 + ra) * K + csrc * 8;
    const u16* sB0 = B + (size_t)(n0 + ra) * K + csrc * 8;
    const u16* sB1 = B + (size_t)(n0 + 128 + ra) * K + csrc * 8;
    const int dst0 = tid * 8, dst1 = 4096 + tid * 8;   // elems (16 B / thread)

    const int swz = (fm >> 1) & 3;
    const int aRd = (wr * 128 + fm) * 32 + ((kq ^ swz) << 3);
    const int bRd = (wc * 64 + fm) * 32 + ((kq ^ swz) << 3);

    f32x4 acc[8][4] = {};
    bf16x8 af[4], bfr[4];

    STG(0, 0, 0, 0);
    STG(1, 0, 0, 0);
    STG(0, 0, 1, 32);
    STG(1, 0, 1, 32);
    STG(0, 1, 0, 64);
    STG(1, 1, 0, 64);
    VM8;
    __builtin_amdgcn_s_barrier();

    const int NITER = K >> 7;                    // 2 K-tiles (BK=64) per iteration
    #pragma unroll 1
    for (int it = 0; it < NITER; ++it) {
        const int kT1 = (it * 2 + 1) * 64;
        const int kT2 = kT1 + 64, kT3 = kT1 + 128;
        const bool ok = (it < NITER - 1);
        PH(0, 0, 0, true,  STG(0, 1, 1, kT1 + 32), );
        PH(0, 0, 4, false, STG(1, 1, 1, kT1 + 32), VM8);
        PH(0, 1, 0, true,  if (ok) STG(0, 0, 0, kT2), );
        PH(0, 1, 4, false, if (ok) STG(1, 0, 0, kT2),
           if (ok) { VM8; } else { VM4; });
        PH(1, 0, 0, true,  if (ok) STG(0, 0, 1, kT2 + 32), );
        PH(1, 0, 4, false, if (ok) STG(1, 0, 1, kT2 + 32),
           if (ok) { VM8; } else { VM0; });
        PH(1, 1, 0, true,  if (ok) STG(0, 1, 0, kT3), );
        PH(1, 1, 4, false, if (ok) STG(1, 1, 0, kT3),
           if (ok) { VM8; });
    }

    const int col = lane & 15, rb2 = (lane >> 4) * 4;
    #pragma unroll
    for (int ii = 0; ii < 8; ++ii)
        #pragma unroll
        for (int j = 0; j < 4; ++j)
            #pragma unroll
            for (int rg = 0; rg < 4; ++rg) {
                int m = m0 + wr * 128 + ii * 16 + rb2 + rg;
                if (m < M_valid) {
                    int n = n0 + wc * 64 + j * 16 + col;
                    float v = acc[ii][j][rg];
                    size_t idx = (size_t)m * N + n;
                    if (OUT == 0) ((float*)Cv)[idx] = v;
                    else          ((u16*)Cv)[idx] = f32_to_bf16(v);
                }
            }
}

// blocks 0..767: V proj (N=1536), XCD-swizzled. blocks 768..773: q proj.
__global__ __launch_bounds__(512, 2)
void gemm_main(const u16* __restrict__ xqp, const u16* __restrict__ wqb,
               float* __restrict__ qout,
               const u16* __restrict__ xb, const u16* __restrict__ wvb,
               u16* __restrict__ vbuf)
{
    __shared__ u16 lds[65536];                   // 128 KiB
    const int blk = blockIdx.x;
    if (blk < 768) {
        int g = blk & 7, s = blk >> 3;           // 96 blocks per XCD class
        int mb = g * 16 + s / 6, nb = s % 6;
        gemm256_body<1>(xb, wvb, vbuf, MKV, Cc, Cc, mb * 256, nb * 256, lds);
    } else {
        int nb = blk - 768;
        gemm256_body<0>(xqp, wqb, qout, 64, Cc, Cc, 0, nb * 256, lds);
    }
}

// ---------------- qk prep: qk[b,h,r,:] = Wk_h^T @ q[b,r,h,:]  (2.4 GFLOP) ------------
__global__ __launch_bounds__(256)
void qk_kernel(const float* __restrict__ qout, const u16* __restrict__ wkb,
               u16* __restrict__ qkb)
{
    const int h = blockIdx.x % Hh, b = blockIdx.x / Hh;   // 192 blocks
    const int tid = threadIdx.x;
    __shared__ float qs[RR][HD];
    for (int i = tid; i < RR * HD; i += 256)
        qs[i >> 6][i & 63] = qout[(size_t)(b * RR + (i >> 6)) * Cc + h * HD + (i & 63)];
    __syncthreads();
    float acc[RR][6] = {};
    for (int d = 0; d < HD; ++d) {
        float wv[6];
        #pragma unroll
        for (int cc = 0; cc < 6; ++cc)
            wv[cc] = bflo((u32)wkb[(size_t)(h * HD + d) * Cc + cc * 256 + tid]);
        #pragma unroll
        for (int r = 0; r < RR; ++r) {
            float qv = qs[r][d];
            #pragma unroll
            for (int cc = 0; cc < 6; ++cc) acc[r][cc] += qv * wv[cc];
        }
    }
    #pragma unroll
    for (int r = 0; r < RR; ++r)
        #pragma unroll
        for (int cc = 0; cc < 6; ++cc)
            qkb[(size_t)((b * Hh + h) * RR + r) * Cc + cc * 256 + tid] = f32_to_bf16(acc[r][cc]);
}

// ---------------- attention via S = QK @ x^T (MFMA), softmax, PV ----------------
// grid (32 chunks, 8 b), 512 threads (8 waves 2Mx4N). M=192 rows (h*8+r), N=128 keys.
// LDS union (bytes):
//   GEMM: A dbuf [2][192*64] @0/24576; B dbuf [2][128*64] @49152/65536  (end 81920)
//   P f32 [192][132] @0 (101376) -- written after GEMM done
//   mk int [8][128] @101376 ; rowred f32 [192][4] @105472
//   V bf16 dbuf [2][128*64] @108544/124928 (end 141312)
__global__ __launch_bounds__(512)
void attn_sx_kernel(const u16* __restrict__ qkb, const u16* __restrict__ xb,
                    const u16* __restrict__ vbuf, const int* __restrict__ mask,
                    float* __restrict__ opart, float* __restrict__ mstat,
                    float* __restrict__ lstat)
{
    __shared__ char smem[141312];
    const int c = blockIdx.x, b = blockIdx.y;
    const int tid = threadIdx.x;
    const int lane = tid & 63, w = tid >> 6;
    const int wr = w >> 2, wc = w & 3;
    const int fm = lane & 15, kq = lane >> 4;

    int*   mk = (int*)(smem + 101376);
    float* rowred = (float*)(smem + 105472);
    float* P  = (float*)smem;

    // mask chunk -> LDS
    for (int idx = tid; idx < RR * CKK; idx += 512) {
        int r = idx >> 7, jj = idx & 127;
        int jg = c * CKK + jj;
        mk[idx] = (jg < RR) ? (jg == r)
                            : mask[(size_t)(b * RR + r) * (Nn - RR) + (jg - RR)];
    }

    // ---- S-GEMM: S[192,128] = qk_b[192,1536] @ x_chunk[128,1536]^T ----
    const int tr = tid >> 3;
    const int csrc = (tid & 7) ^ (tr & 7);
    const u16* aSrc[3]; const u16* bSrc[2];
    {
        const u16* qk_b = qkb + (size_t)b * 192 * Cc;
        const u16* x_c  = xb + (size_t)(b * Nn + c * CKK) * Cc;
        #pragma unroll
        for (int k = 0; k < 3; ++k) aSrc[k] = qk_b + (size_t)(k * 64 + tr) * Cc + csrc * 8;
        #pragma unroll
        for (int k = 0; k < 2; ++k) bSrc[k] = x_c + (size_t)(k * 64 + tr) * Cc + csrc * 8;
    }

    f32x4 acc[6][2] = {};

    #define ASTG(BUF, KT) do {                                                           \
        _Pragma("unroll")                                                                \
        for (int k = 0; k < 3; ++k)                                                      \
            __builtin_amdgcn_global_load_lds(                                            \
                (const __attribute__((address_space(1))) void*)(aSrc[k] + (KT) * 64),    \
                (__attribute__((address_space(3))) void*)(smem + (BUF) * 24576           \
                    + (k * 4096 + tid * 8) * 2), 16, 0, 0);                              \
        _Pragma("unroll")                                                                \
        for (int k = 0; k < 2; ++k)                                                      \
            __builtin_amdgcn_global_load_lds(                                            \
                (const __attribute__((address_space(1))) void*)(bSrc[k] + (KT) * 64),    \
                (__attribute__((address_space(3))) void*)(smem + 49152 + (BUF) * 16384   \
                    + (k * 4096 + tid * 8) * 2), 16, 0, 0);                              \
    } while (0)

    ASTG(0, 0);
    __syncthreads();
    #pragma unroll 1
    for (int t = 0; t < 24; ++t) {
        int cur = t & 1;
        if (t < 23) ASTG(cur ^ 1, t + 1);
        const u16* As = (const u16*)(smem + cur * 24576);
        const u16* Bs = (const u16*)(smem + 49152 + cur * 16384);
        #pragma unroll
        for (int ks = 0; ks < 2; ++ks) {
            bf16x8 af[6], bfr[2];
            #pragma unroll
            for (int j = 0; j < 2; ++j) {
                int r = wc * 32 + j * 16 + fm;
                int cc = ks * 4 + kq;
                bfr[j] = *(const bf16x8*)&Bs[r * 64 + ((cc ^ (r & 7)) << 3)];
            }
            #pragma unroll
            for (int i = 0; i < 6; ++i) {
                int r = wr * 96 + i * 16 + fm;
                int cc = ks * 4 + kq;
                af[i] = *(const bf16x8*)&As[r * 64 + ((cc ^ (r & 7)) << 3)];
            }
            #pragma unroll
            for (int i = 0; i < 6; ++i)
                #pragma unroll
                for (int j = 0; j < 2; ++j)
                    acc[i][j] = __builtin_amdgcn_mfma_f32_16x16x32_bf16(af[i], bfr[j], acc[i][j], 0, 0, 0);
        }
        __syncthreads();   // drains vmcnt(0): next tile landed; all waves done with buf
    }

    // stage V for h=0 early (disjoint LDS region; overlaps softmax)
    #define VSTG(BUF, H) do {                                                            \
        _Pragma("unroll")                                                                \
        for (int k = 0; k < 2; ++k)                                                      \
            __builtin_amdgcn_global_load_lds(                                            \
                (const __attribute__((address_space(1))) void*)(vbuf                     \
                    + (size_t)(b * Nn + c * CKK + k * 64 + tr) * Cc + (H) * HD + csrc * 8), \
                (__attribute__((address_space(3))) void*)(smem + 108544 + (BUF) * 16384  \
                    + (k * 4096 + tid * 8) * 2), 16, 0, 0);                              \
    } while (0)
    VSTG(0, 0);

    // ---- masked softmax over register-resident S ----
    const int rb = (lane >> 4) * 4;
    const int col = lane & 15;
    float RM[6][4], LS[6][4];
    #pragma unroll
    for (int i = 0; i < 6; ++i)
        #pragma unroll
        for (int jf = 0; jf < 2; ++jf)
            #pragma unroll
            for (int rg = 0; rg < 4; ++rg) {
                int m = wr * 96 + i * 16 + rb + rg;
                int jj = wc * 32 + jf * 16 + col;
                if (!mk[(m & 7) * CKK + jj]) acc[i][jf][rg] = -INFINITY;
            }
    #pragma unroll
    for (int i = 0; i < 6; ++i)
        #pragma unroll
        for (int rg = 0; rg < 4; ++rg) {
            float v = fmaxf(acc[i][0][rg], acc[i][1][rg]);
            v = fmaxf(v, __shfl_xor(v, 1));
            v = fmaxf(v, __shfl_xor(v, 2));
            v = fmaxf(v, __shfl_xor(v, 4));
            v = fmaxf(v, __shfl_xor(v, 8));
            RM[i][rg] = v;
        }
    if (col == 0)
        #pragma unroll
        for (int i = 0; i < 6; ++i)
            #pragma unroll
            for (int rg = 0; rg < 4; ++rg)
                rowred[(wr * 96 + i * 16 + rb + rg) * 4 + wc] = RM[i][rg];
    __syncthreads();
    #pragma unroll
    for (int i = 0; i < 6; ++i)
        #pragma unroll
        for (int rg = 0; rg < 4; ++rg) {
            f32x4 q4 = *(const f32x4*)&rowred[(wr * 96 + i * 16 + rb + rg) * 4];
            RM[i][rg] = fmaxf(fmaxf(q4[0], q4[1]), fmaxf(q4[2], q4[3]));
        }
    __syncthreads();
    #pragma unroll
    for (int i = 0; i < 6; ++i)
        #pragma unroll
        for (int rg = 0; rg < 4; ++rg) {
            float mg = fmaxf(RM[i][rg], -1e30f);
            float s = 0.f;
            #pragma unroll
            for (int jf = 0; jf < 2; ++jf) {
                float p = __expf(acc[i][jf][rg] - mg);
                acc[i][jf][rg] = p;
                s += p;
            }
            s += __shfl_xor(s, 1);
            s += __shfl_xor(s, 2);
            s += __shfl_xor(s, 4);
            s += __shfl_xor(s, 8);
            LS[i][rg] = s;
        }
    if (col == 0)
        #pragma unroll
        for (int i = 0; i < 6; ++i)
            #pragma unroll
            for (int rg = 0; rg < 4; ++rg)
                rowred[(wr * 96 + i * 16 + rb + rg) * 4 + wc] = LS[i][rg];
    __syncthreads();
    #pragma unroll
    for (int i = 0; i < 6; ++i)
        #pragma unroll
        for (int rg = 0; rg < 4; ++rg) {
            f32x4 q4 = *(const f32x4*)&rowred[(wr * 96 + i * 16 + rb + rg) * 4];
            LS[i][rg] = q4[0] + q4[1] + q4[2] + q4[3];
        }
    if (wc == 0 && col == 0)
        #pragma unroll
        for (int i = 0; i < 6; ++i)
            #pragma unroll
            for (int rg = 0; rg < 4; ++rg) {
                int m = wr * 96 + i * 16 + rb + rg;
                size_t si = ((size_t)(b * Hh + (m >> 3)) * ACH + c) * RR + (m & 7);
                mstat[si] = RM[i][rg];
                lstat[si] = LS[i][rg];
            }
    // P (unnormalized exp) -> LDS f32 [192][132]
    #pragma unroll
    for (int i = 0; i < 6; ++i)
        #pragma unroll
        for (int jf = 0; jf < 2; ++jf)
            #pragma unroll
            for (int rg = 0; rg < 4; ++rg) {
                int m = wr * 96 + i * 16 + rb + rg;
                P[m * 132 + wc * 32 + jf * 16 + col] = acc[i][jf][rg];
            }
    __syncthreads();   // drains V h=0 stage too

    // ---- PV: o[h,r,d] = sum_j P[h*8+r, j] * V[j, h*64+d]; wave = r; dbuf V over h ----
    const int r2 = w;                  // 0..7
    const int dh = lane & 7;           // d-octet: d = dh*8 ..
    const int kjh = lane >> 3;         // j-group of 16
    #pragma unroll 1
    for (int h = 0; h < Hh; ++h) {
        int cur = h & 1;
        if (h < Hh - 1) VSTG(cur ^ 1, h + 1);
        const float* pr = P + (h * RR + r2) * 132 + kjh * 16;
        const u16* vs = (const u16*)(smem + 108544 + cur * 16384);
        float a[8] = {};
        #pragma unroll
        for (int jq = 0; jq < 4; ++jq) {
            f32x4 pv = *(const f32x4*)(pr + jq * 4);
            #pragma unroll
            for (int t = 0; t < 4; ++t) {
                int jl = jq * 4 + t;
                int j = kjh * 16 + jl;
                const uint4 vv = *(const uint4*)&vs[j * 64 + ((dh ^ (jl & 7)) << 3)];
                float p = pv[t];
                a[0] += p * bflo(vv.x); a[1] += p * bfhi(vv.x);
                a[2] += p * bflo(vv.y); a[3] += p * bfhi(vv.y);
                a[4] += p * bflo(vv.z); a[5] += p * bfhi(vv.z);
                a[6] += p * bflo(vv.w); a[7] += p * bfhi(vv.w);
            }
        }
        #pragma unroll
        for (int xx = 0; xx < 8; ++xx) {
            a[xx] += __shfl_xor(a[xx], 8);
            a[xx] += __shfl_xor(a[xx], 16);
            a[xx] += __shfl_xor(a[xx], 32);
        }
        if (kjh == 0) {
            size_t po = ((size_t)(b * Hh + h) * ACH + c) * (RR * HD) + r2 * HD + dh * 8;
            float4 o1 = {a[0], a[1], a[2], a[3]};
            float4 o2 = {a[4], a[5], a[6], a[7]};
            *(float4*)(opart + po) = o1;
            *(float4*)(opart + po + 4) = o2;
        }
        __syncthreads();
    }
}

// ---------------- combine partials -> bf16 attention output ----------------
__global__ __launch_bounds__(256)
void attn_combine_kernel(const float* __restrict__ opart, const float* __restrict__ mstat,
                         const float* __restrict__ lstat, u16* __restrict__ aob)
{
    int idx = blockIdx.x * 256 + threadIdx.x;   // < 64*1536
    int row = idx / Cc, col = idx - row * Cc;
    int b = row >> 3, r = row & 7;
    int h = col >> 6, d = col & 63;
    int bh = b * Hh + h;
    float M = -INFINITY;
    #pragma unroll
    for (int c = 0; c < ACH; ++c)
        M = fmaxf(M, mstat[((size_t)bh * ACH + c) * RR + r]);
    float L = 0.f, O = 0.f;
    #pragma unroll
    for (int c = 0; c < ACH; ++c) {
        size_t si = ((size_t)bh * ACH + c) * RR + r;
        float w = __expf(mstat[si] - M);
        L += w * lstat[si];
        O += w * opart[((size_t)bh * ACH + c) * (RR * HD) + r * HD + d];
    }
    aob[(size_t)row * Cc + col] = f32_to_bf16(O / L);
}

// ---------------- output projection, split-K x4 with f32 atomics ----------------
__global__ __launch_bounds__(256, 3)
void gemm_out(const u16* __restrict__ aob, const u16* __restrict__ wpb,
              float* __restrict__ out, const float* __restrict__ bp)
{
    __shared__ u16 As[128 * 64];
    __shared__ u16 Bs[128 * 64];
    const int nb = blockIdx.x;                   // 0..11
    const int z = blockIdx.y;                    // 0..3
    gemm_body64<2>(aob, wpb, out, (z == 0) ? bp : nullptr,
                   64, Cc, Cc, 0, nb * 128, z * 384, (z + 1) * 384, As, Bs);
}

// ---------------- launch ----------------
extern "C" void kernel_launch(void* const* d_in, const int* in_sizes, int n_in,
                              void* d_out, int out_size, void* d_ws, size_t ws_size,
                              hipStream_t stream)
{
    const float* x    = (const float*)d_in[0];
    const int*   mask = (const int*)d_in[1];
    const float* Wq   = (const float*)d_in[2];
    const float* Wk   = (const float*)d_in[3];
    const float* Wv   = (const float*)d_in[4];
    const float* Wp   = (const float*)d_in[5];
    const float* bp   = (const float*)d_in[6];

    char* ws = (char*)d_ws;
    u16*   xb     = (u16*)(ws);                       // 100,663,296  x bf16 [32768,1536]
    u16*   wkvb   = (u16*)(ws + 100663296);           //   9,437,184  [Wk;Wv] bf16
    u16*   wqb    = (u16*)(ws + 110100480);           //   4,718,592  Wq bf16
    u16*   wpb    = (u16*)(ws + 114819072);           //   4,718,592  Wp bf16
    u16*   vbuf   = (u16*)(ws + 119537664);           // 100,663,296  v bf16 [32768,1536]
    u16*   qkb    = (u16*)(ws + 220200960);           //   4,718,592  qk bf16 [1536,1536]
    u16*   xqp    = (u16*)(ws + 224919552);           //     393,216  q input padded [128,1536]
    float* qout   = (float*)(ws + 225312768);         //     786,432  q proj f32 [128,1536]
    u16*   aob    = (u16*)(ws + 226099200);           //     393,216  attn out padded [128,1536]
    float* opart  = (float*)(ws + 226492416);         //  12,582,912
    float* mstat  = (float*)(ws + 239075328);         //     196,608
    float* lstat  = (float*)(ws + 239271936);         //     196,608

    u16* wvb = wkvb + 2359296;   // Wv half

    // 1: all casts + q gather + zero fills
    prep_kernel<<<58752, 256, 0, stream>>>(x, Wk, Wv, Wq, Wp, xb, wkvb, wqb, wpb,
                                           xqp, aob, (float*)d_out);
    // 2: V proj (blocks 0..767) + q proj (blocks 768..773)
    gemm_main<<<774, 512, 0, stream>>>(xqp, wqb, qout, xb, wvb, vbuf);
    // 3: qk = Wk_h^T q
    qk_kernel<<<192, 256, 0, stream>>>(qout, wkvb, qkb);
    // 4: attention (S-GEMM + softmax + PV), 32 chunks x 8 b
    attn_sx_kernel<<<dim3(ACH, Bb), 512, 0, stream>>>(qkb, xb, vbuf, mask,
                                                      opart, mstat, lstat);
    // 5: combine
    attn_combine_kernel<<<384, 256, 0, stream>>>(opart, mstat, lstat, aob);
    // 6: output projection, split-K atomics (d_out zeroed by prep)
    gemm_out<<<dim3(12, 4), 256, 0, stream>>>(aob, wpb, (float*)d_out, bp);
}